// Round 8
// baseline (67.646 us; speedup 1.0000x reference)
//
#include <hip/hip_runtime.h>
#include <hip/hip_bf16.h>

// DLRM-like, round 8: megakernel + non-temporal hints on streaming traffic
// (gather + out) so it stops evicting restaged weights from L2.
// (round 7 failed to compile: __builtin_nontemporal_load needs ext_vector
//  types, not HIP_vector_type float4.)
//
// ws layout (bytes):
//   [0,      32768)   W0t 512x32  bf16 (k>=13 zero)
//   [32768,  294912)  W1t 256x512 bf16
//   [294912, 327680)  W2t 64x256  bf16
//   [327680, 540672)  Wtt 256x416 bf16 (k>=389 zero)

#define BATCH   16384
#define NSPARSE 26
#define VOCAB   100000
#define EMB     64
#define KTOP    416
#define KREAL   389
#define SPB     32
#define ASTR    424   // shorts; 212 dw % 32 = 20 -> <=2-way on frag reads
#define X1STR   520   // 260 dw % 32 = 4  -> <=2-way
#define X2STR   264   // 132 dw % 32 = 4  -> <=2-way

typedef __attribute__((ext_vector_type(8)))  short bf16x8;
typedef __attribute__((ext_vector_type(4)))  short s16x4;
typedef __attribute__((ext_vector_type(4)))  float f32x4;
typedef __attribute__((ext_vector_type(16))) float f32x16;

__device__ inline void gload_lds16(const void* g, void* l) {
    __builtin_amdgcn_global_load_lds(
        (const __attribute__((address_space(1))) void*)g,
        (__attribute__((address_space(3))) void*)l, 16, 0, 0);
}

__device__ inline short f2bf(float x) {
    __hip_bfloat16 h = __float2bfloat16(x);
    return *reinterpret_cast<short*>(&h);
}

__device__ inline f32x4 ntload4(const float* p) {
    return __builtin_nontemporal_load((const f32x4*)p);
}

// ------------------------------------------------- prep: tiled transpose ----
// src f32 [K][N] -> dst bf16 [N][Kpad], zero for k>=K. 32x32 tiles via LDS.
__global__ __launch_bounds__(256)
void prep_weights(const float* __restrict__ W0, const float* __restrict__ W1,
                  const float* __restrict__ W2, const float* __restrict__ Wt,
                  short* __restrict__ W0t, short* __restrict__ W1t,
                  short* __restrict__ W2t, short* __restrict__ Wtt)
{
    __shared__ float tile[32][36];
    int b = blockIdx.x, t = threadIdx.x;
    const float* src; short* dst; int K, N, Kpad, k0, n0;
    if (b < 16)        {              src = W0; dst = W0t; K = 13;  N = 512; Kpad = 32;  k0 = 0;           n0 = b * 32; }
    else if (b < 144)  { int i = b - 16;  src = W1; dst = W1t; K = 512; N = 256; Kpad = 512; k0 = (i >> 3) * 32; n0 = (i & 7) * 32; }
    else if (b < 160)  { int i = b - 144; src = W2; dst = W2t; K = 256; N = 64;  Kpad = 256; k0 = (i >> 1) * 32; n0 = (i & 1) * 32; }
    else               { int i = b - 160; src = Wt; dst = Wtt; K = 389; N = 256; Kpad = 416; k0 = (i >> 3) * 32; n0 = (i & 7) * 32; }

    int r = t >> 3, c4 = (t & 7) * 4;
    int gr = k0 + r;
    float4 v = make_float4(0.f, 0.f, 0.f, 0.f);
    if (gr < K) v = *(const float4*)(src + (size_t)gr * N + n0 + c4);
    tile[r][c4 + 0] = v.x; tile[r][c4 + 1] = v.y;
    tile[r][c4 + 2] = v.z; tile[r][c4 + 3] = v.w;
    __syncthreads();
    s16x4 o;
    #pragma unroll
    for (int j = 0; j < 4; ++j) o[j] = f2bf(tile[c4 + j][r]);
    *(s16x4*)&dst[(size_t)(n0 + r) * Kpad + k0 + c4] = o;
}

// ------------------------------------------------------------ megakernel ----
__global__ __launch_bounds__(256, 2)
void fused_all(const int* __restrict__ sparse, const float* __restrict__ tables,
               const float* __restrict__ D,
               const short* __restrict__ W0t, const float* __restrict__ b0,
               const short* __restrict__ W1t, const float* __restrict__ b1,
               const short* __restrict__ W2t, const float* __restrict__ b2,
               const short* __restrict__ Wtt, const float* __restrict__ bt,
               float* __restrict__ out)
{
    // As 27136 | X1s(33280; X2s aliases) | Bst 16384 | Ds 2048 = 78848 B
    __shared__ __align__(16) char smem[78848];
    short* As  = (short*)(smem);
    short* X1s = (short*)(smem + 27136);
    short* X2s = (short*)(smem + 27136);   // alias: X1s dead after phase-1 loop
    short* Bst = (short*)(smem + 60416);
    short* Ds  = (short*)(smem + 76800);

    int tid = threadIdx.x;
    int w = tid >> 6, lane = tid & 63;
    int lr = lane & 15, lg = lane >> 4;
    int wr = w >> 1, wc = w & 1;
    int swz = (lg ^ (lr & 3)) * 8;         // bank-conflict fix for Bst reads
    int sbase = blockIdx.x * SPB;

    // stage Ds (32x13 f32 -> bf16, pad k to 32) + zero As pad cols 389..415
    for (int x = tid; x < SPB * 13; x += 256) {
        int r = x / 13, k = x - r * 13;
        Ds[r * 32 + k] = f2bf(D[(size_t)sbase * 13 + x]);
    }
    for (int x = tid; x < SPB * 19; x += 256) {
        int r = x / 19, k = 13 + (x - r * 19);
        Ds[r * 32 + k] = 0;
    }
    for (int x = tid; x < SPB * 27; x += 256) {
        int r = x / 27, c = x - r * 27;
        As[r * ASTR + KREAL + c] = 0;
    }
    __syncthreads();

    // ---- gram phase: wave w -> samples w*8..w*8+7, 2-deep load pipeline ----
    auto gram_phase = [&]() {
        int row = lane & 31, half = lane >> 5;
        // lanes with row>=26 read row 0; their output lands in gram rows/cols
        // >=26 which the triangle scatter (r<c<26) never reads.
        int srow = (row < NSPARSE) ? row : 0;
        int idxv[8];
        #pragma unroll
        for (int li = 0; li < 8; ++li)
            idxv[li] = __builtin_nontemporal_load(
                &sparse[(sbase + w * 8 + li) * NSPARSE + srow]);

        f32x4 Ca[4], Cb[4], Na[4], Nb[4];
        {
            const float* rp = tables + ((long)srow * VOCAB + idxv[0]) * EMB + half * 8;
            #pragma unroll
            for (int t = 0; t < 4; ++t) {
                Ca[t] = ntload4(rp + t * 16);
                Cb[t] = ntload4(rp + t * 16 + 4);
            }
        }
        #pragma unroll
        for (int li = 0; li < 8; ++li) {
            if (li < 7) {
                const float* rp = tables + ((long)srow * VOCAB + idxv[li + 1]) * EMB + half * 8;
                #pragma unroll
                for (int t = 0; t < 4; ++t) {
                    Na[t] = ntload4(rp + t * 16);
                    Nb[t] = ntload4(rp + t * 16 + 4);
                }
            }
            f32x16 acc = {};
            #pragma unroll
            for (int t = 0; t < 4; ++t) {
                bf16x8 f;
                #pragma unroll
                for (int j = 0; j < 4; ++j) f[j] = f2bf(Ca[t][j]);
                #pragma unroll
                for (int j = 0; j < 4; ++j) f[4 + j] = f2bf(Cb[t][j]);
                acc = __builtin_amdgcn_mfma_f32_32x32x16_bf16(f, f, acc, 0, 0, 0);
            }
            int c = row;
            if (c < NSPARSE) {
                #pragma unroll
                for (int reg = 0; reg < 16; ++reg) {
                    int r = (reg & 3) + 8 * (reg >> 2) + 4 * half;
                    if (r < c) {
                        int p = r * (2 * NSPARSE - r - 1) / 2 + (c - r - 1);
                        As[(w * 8 + li) * ASTR + 64 + p] = f2bf(acc[reg]);
                    }
                }
            }
            #pragma unroll
            for (int t = 0; t < 4; ++t) { Ca[t] = Na[t]; Cb[t] = Nb[t]; }
        }
    };

    // ---- MLP chain: 32 rows, all in LDS ----
    auto mlp_phase = [&]() {
        // phase 0: X1 = relu(Ds @ W0^T + b0): 32x512, K=32 (B read from global)
        {
            bf16x8 a = *(const bf16x8*)&Ds[(wr * 16 + lr) * 32 + lg * 8];
            f32x4 acc[16] = {};
            #pragma unroll
            for (int ni = 0; ni < 16; ++ni) {
                bf16x8 b = *(const bf16x8*)(W0t + (size_t)(wc * 256 + ni * 16 + lr) * 32 + lg * 8);
                acc[ni] = __builtin_amdgcn_mfma_f32_16x16x32_bf16(a, b, acc[ni], 0, 0, 0);
            }
            #pragma unroll
            for (int ni = 0; ni < 16; ++ni) {
                int col = wc * 256 + ni * 16 + lr;
                float bv = b0[col];
                #pragma unroll
                for (int j = 0; j < 4; ++j) {
                    int r = wr * 16 + lg * 4 + j;
                    X1s[r * X1STR + col] = f2bf(fmaxf(acc[ni][j] + bv, 0.f));
                }
            }
        }
        // phase 1: X2 = relu(X1 @ W1^T + b1): 32x256, K=512 (16 steps)
        {
            f32x4 acc[8] = {};
            for (int k0 = 0; k0 < 512; k0 += 32) {
                #pragma unroll
                for (int rd = 0; rd < 4; ++rd) {
                    int slot = rd * 256 + tid;
                    int n = slot >> 2, kc = slot & 3;
                    gload_lds16(W1t + (size_t)n * 512 + k0 + (kc ^ (n & 3)) * 8, &Bst[slot * 8]);
                }
                __syncthreads();
                bf16x8 a = *(const bf16x8*)&X1s[(wr * 16 + lr) * X1STR + k0 + lg * 8];
                #pragma unroll
                for (int ni = 0; ni < 8; ++ni) {
                    int n = wc * 128 + ni * 16 + lr;
                    bf16x8 b = *(const bf16x8*)&Bst[n * 32 + swz];
                    acc[ni] = __builtin_amdgcn_mfma_f32_16x16x32_bf16(a, b, acc[ni], 0, 0, 0);
                }
                __syncthreads();
            }
            #pragma unroll
            for (int ni = 0; ni < 8; ++ni) {
                int col = wc * 128 + ni * 16 + lr;
                float bv = b1[col];
                #pragma unroll
                for (int j = 0; j < 4; ++j) {
                    int r = wr * 16 + lg * 4 + j;
                    X2s[r * X2STR + col] = f2bf(fmaxf(acc[ni][j] + bv, 0.f));
                }
            }
        }
        // phase 2: dense_out = relu(X2 @ W2^T + b2): 32x64, K=256 (8 steps)
        {
            f32x4 acc[2] = {};
            for (int k0 = 0; k0 < 256; k0 += 32) {
                {
                    int n = tid >> 2, kc = tid & 3;
                    gload_lds16(W2t + (size_t)n * 256 + k0 + (kc ^ (n & 3)) * 8, &Bst[tid * 8]);
                }
                __syncthreads();
                bf16x8 a = *(const bf16x8*)&X2s[(wr * 16 + lr) * X2STR + k0 + lg * 8];
                #pragma unroll
                for (int ni = 0; ni < 2; ++ni) {
                    int n = wc * 32 + ni * 16 + lr;
                    bf16x8 b = *(const bf16x8*)&Bst[n * 32 + swz];
                    acc[ni] = __builtin_amdgcn_mfma_f32_16x16x32_bf16(a, b, acc[ni], 0, 0, 0);
                }
                __syncthreads();
            }
            #pragma unroll
            for (int ni = 0; ni < 2; ++ni) {
                int col = wc * 32 + ni * 16 + lr;
                float bv = b2[col];
                #pragma unroll
                for (int j = 0; j < 4; ++j) {
                    int r = wr * 16 + lg * 4 + j;
                    As[r * ASTR + col] = f2bf(fmaxf(acc[ni][j] + bv, 0.f));
                }
            }
        }
    };

    // parity stagger: half the blocks gather first, half compute first
    if (blockIdx.x & 1) { mlp_phase(); gram_phase(); }
    else                { gram_phase(); mlp_phase(); }

    // ---- top GEMM: out(32x256) = As(32xK416) @ Wtt^T + bt ----
    {
        f32x4 acc[8] = {};
        for (int k0 = 0; k0 < KTOP; k0 += 32) {
            #pragma unroll
            for (int rd = 0; rd < 4; ++rd) {
                int slot = rd * 256 + tid;
                int n = slot >> 2, kc = slot & 3;
                gload_lds16(Wtt + (size_t)n * KTOP + k0 + (kc ^ (n & 3)) * 8, &Bst[slot * 8]);
            }
            __syncthreads();
            bf16x8 a = *(const bf16x8*)&As[(wr * 16 + lr) * ASTR + k0 + lg * 8];
            #pragma unroll
            for (int ni = 0; ni < 8; ++ni) {
                int n = wc * 128 + ni * 16 + lr;
                bf16x8 b = *(const bf16x8*)&Bst[n * 32 + swz];
                acc[ni] = __builtin_amdgcn_mfma_f32_16x16x32_bf16(a, b, acc[ni], 0, 0, 0);
            }
            __syncthreads();
        }
        #pragma unroll
        for (int ni = 0; ni < 8; ++ni) {
            int col = wc * 128 + ni * 16 + lr;
            float bv = bt[col];
            #pragma unroll
            for (int j = 0; j < 4; ++j) {
                int r = wr * 16 + lg * 4 + j;
                __builtin_nontemporal_store(
                    acc[ni][j] + bv, &out[(size_t)(sbase + r) * 256 + col]);
            }
        }
    }
}

// -------------------------------------------------------------- launch ----
extern "C" void kernel_launch(void* const* d_in, const int* in_sizes, int n_in,
                              void* d_out, int out_size, void* d_ws, size_t ws_size,
                              hipStream_t stream)
{
    const float* dense  = (const float*)d_in[0];
    const int*   sparse = (const int*)  d_in[1];
    const float* tables = (const float*)d_in[2];
    const float* W0     = (const float*)d_in[3];
    const float* b0     = (const float*)d_in[4];
    const float* W1     = (const float*)d_in[5];
    const float* b1     = (const float*)d_in[6];
    const float* W2     = (const float*)d_in[7];
    const float* b2     = (const float*)d_in[8];
    const float* Wt     = (const float*)d_in[9];
    const float* bt     = (const float*)d_in[10];
    float* out = (float*)d_out;

    char* ws = (char*)d_ws;
    short* W0t = (short*)(ws);
    short* W1t = (short*)(ws + 32768);
    short* W2t = (short*)(ws + 294912);
    short* Wtt = (short*)(ws + 327680);

    prep_weights<<<264, 256, 0, stream>>>(W0, W1, W2, Wt, W0t, W1t, W2t, Wtt);

    fused_all<<<BATCH / SPB, 256, 0, stream>>>(sparse, tables, dense,
                                               W0t, b0, W1t, b1, W2t, b2,
                                               Wtt, bt, out);
}

// Round 9
// 52.032 us; speedup vs baseline: 1.3001x; 1.3001x over previous
//
#include <hip/hip_runtime.h>
#include <hip/hip_bf16.h>

// DLRM-like, round 9: r5 megakernel semantics (nt hints reverted — r8 showed
// the gather's cache residency is load-bearing) + FIXED phase stagger:
// co-resident blocks are (i, i+256), so parity must be bit 8, not bit 0.
//
// ws layout (bytes):
//   [0,      32768)   W0t 512x32  bf16 (k>=13 zero)
//   [32768,  294912)  W1t 256x512 bf16
//   [294912, 327680)  W2t 64x256  bf16
//   [327680, 540672)  Wtt 256x416 bf16 (k>=389 zero)

#define BATCH   16384
#define NSPARSE 26
#define VOCAB   100000
#define EMB     64
#define KTOP    416
#define KREAL   389
#define SPB     32
#define ASTR    424   // shorts; 212 dw % 32 = 20 -> <=2-way on frag reads
#define X1STR   520   // 260 dw % 32 = 4  -> <=2-way
#define X2STR   264   // 132 dw % 32 = 4  -> <=2-way

typedef __attribute__((ext_vector_type(8)))  short bf16x8;
typedef __attribute__((ext_vector_type(4)))  short s16x4;
typedef __attribute__((ext_vector_type(4)))  float f32x4;
typedef __attribute__((ext_vector_type(16))) float f32x16;

__device__ inline void gload_lds16(const void* g, void* l) {
    __builtin_amdgcn_global_load_lds(
        (const __attribute__((address_space(1))) void*)g,
        (__attribute__((address_space(3))) void*)l, 16, 0, 0);
}

__device__ inline short f2bf(float x) {
    __hip_bfloat16 h = __float2bfloat16(x);
    return *reinterpret_cast<short*>(&h);
}

// ------------------------------------------------- prep: tiled transpose ----
// src f32 [K][N] -> dst bf16 [N][Kpad], zero for k>=K. 32x32 tiles via LDS.
__global__ __launch_bounds__(256)
void prep_weights(const float* __restrict__ W0, const float* __restrict__ W1,
                  const float* __restrict__ W2, const float* __restrict__ Wt,
                  short* __restrict__ W0t, short* __restrict__ W1t,
                  short* __restrict__ W2t, short* __restrict__ Wtt)
{
    __shared__ float tile[32][36];
    int b = blockIdx.x, t = threadIdx.x;
    const float* src; short* dst; int K, N, Kpad, k0, n0;
    if (b < 16)        {              src = W0; dst = W0t; K = 13;  N = 512; Kpad = 32;  k0 = 0;           n0 = b * 32; }
    else if (b < 144)  { int i = b - 16;  src = W1; dst = W1t; K = 512; N = 256; Kpad = 512; k0 = (i >> 3) * 32; n0 = (i & 7) * 32; }
    else if (b < 160)  { int i = b - 144; src = W2; dst = W2t; K = 256; N = 64;  Kpad = 256; k0 = (i >> 1) * 32; n0 = (i & 1) * 32; }
    else               { int i = b - 160; src = Wt; dst = Wtt; K = 389; N = 256; Kpad = 416; k0 = (i >> 3) * 32; n0 = (i & 7) * 32; }

    int r = t >> 3, c4 = (t & 7) * 4;
    int gr = k0 + r;
    float4 v = make_float4(0.f, 0.f, 0.f, 0.f);
    if (gr < K) v = *(const float4*)(src + (size_t)gr * N + n0 + c4);
    tile[r][c4 + 0] = v.x; tile[r][c4 + 1] = v.y;
    tile[r][c4 + 2] = v.z; tile[r][c4 + 3] = v.w;
    __syncthreads();
    s16x4 o;
    #pragma unroll
    for (int j = 0; j < 4; ++j) o[j] = f2bf(tile[c4 + j][r]);
    *(s16x4*)&dst[(size_t)(n0 + r) * Kpad + k0 + c4] = o;
}

// ------------------------------------------------------------ megakernel ----
__global__ __launch_bounds__(256, 2)
void fused_all(const int* __restrict__ sparse, const float* __restrict__ tables,
               const float* __restrict__ D,
               const short* __restrict__ W0t, const float* __restrict__ b0,
               const short* __restrict__ W1t, const float* __restrict__ b1,
               const short* __restrict__ W2t, const float* __restrict__ b2,
               const short* __restrict__ Wtt, const float* __restrict__ bt,
               float* __restrict__ out)
{
    // As 27136 | X1s(33280; X2s aliases) | Bst 16384 | Ds 2048 = 78848 B
    __shared__ __align__(16) char smem[78848];
    short* As  = (short*)(smem);
    short* X1s = (short*)(smem + 27136);
    short* X2s = (short*)(smem + 27136);   // alias: X1s dead after phase-1 loop
    short* Bst = (short*)(smem + 60416);
    short* Ds  = (short*)(smem + 76800);

    int tid = threadIdx.x;
    int w = tid >> 6, lane = tid & 63;
    int lr = lane & 15, lg = lane >> 4;
    int wr = w >> 1, wc = w & 1;
    int swz = (lg ^ (lr & 3)) * 8;         // bank-conflict fix for Bst reads
    int sbase = blockIdx.x * SPB;

    // stage Ds (32x13 f32 -> bf16, pad k to 32) + zero As pad cols 389..415
    for (int x = tid; x < SPB * 13; x += 256) {
        int r = x / 13, k = x - r * 13;
        Ds[r * 32 + k] = f2bf(D[(size_t)sbase * 13 + x]);
    }
    for (int x = tid; x < SPB * 19; x += 256) {
        int r = x / 19, k = 13 + (x - r * 19);
        Ds[r * 32 + k] = 0;
    }
    for (int x = tid; x < SPB * 27; x += 256) {
        int r = x / 27, c = x - r * 27;
        As[r * ASTR + KREAL + c] = 0;
    }
    __syncthreads();

    // ---- gram phase: wave w -> samples w*8..w*8+7, 2-deep load pipeline ----
    auto gram_phase = [&]() {
        int row = lane & 31, half = lane >> 5;
        // lanes with row>=26 read row 0; their output lands in gram rows/cols
        // >=26 which the triangle scatter (r<c<26) never reads.
        int srow = (row < NSPARSE) ? row : 0;
        int idxv[8];
        #pragma unroll
        for (int li = 0; li < 8; ++li)
            idxv[li] = sparse[(sbase + w * 8 + li) * NSPARSE + srow];

        f32x4 Ca[4], Cb[4], Na[4], Nb[4];
        {
            const float* rp = tables + ((long)srow * VOCAB + idxv[0]) * EMB + half * 8;
            #pragma unroll
            for (int t = 0; t < 4; ++t) {
                Ca[t] = *(const f32x4*)(rp + t * 16);
                Cb[t] = *(const f32x4*)(rp + t * 16 + 4);
            }
        }
        #pragma unroll
        for (int li = 0; li < 8; ++li) {
            if (li < 7) {
                const float* rp = tables + ((long)srow * VOCAB + idxv[li + 1]) * EMB + half * 8;
                #pragma unroll
                for (int t = 0; t < 4; ++t) {
                    Na[t] = *(const f32x4*)(rp + t * 16);
                    Nb[t] = *(const f32x4*)(rp + t * 16 + 4);
                }
            }
            f32x16 acc = {};
            #pragma unroll
            for (int t = 0; t < 4; ++t) {
                bf16x8 f;
                #pragma unroll
                for (int j = 0; j < 4; ++j) f[j] = f2bf(Ca[t][j]);
                #pragma unroll
                for (int j = 0; j < 4; ++j) f[4 + j] = f2bf(Cb[t][j]);
                acc = __builtin_amdgcn_mfma_f32_32x32x16_bf16(f, f, acc, 0, 0, 0);
            }
            int c = row;
            if (c < NSPARSE) {
                #pragma unroll
                for (int reg = 0; reg < 16; ++reg) {
                    int r = (reg & 3) + 8 * (reg >> 2) + 4 * half;
                    if (r < c) {
                        int p = r * (2 * NSPARSE - r - 1) / 2 + (c - r - 1);
                        As[(w * 8 + li) * ASTR + 64 + p] = f2bf(acc[reg]);
                    }
                }
            }
            #pragma unroll
            for (int t = 0; t < 4; ++t) { Ca[t] = Na[t]; Cb[t] = Nb[t]; }
        }
    };

    // ---- MLP chain: 32 rows, all in LDS ----
    auto mlp_phase = [&]() {
        // phase 0: X1 = relu(Ds @ W0^T + b0): 32x512, K=32 (B read from global)
        {
            bf16x8 a = *(const bf16x8*)&Ds[(wr * 16 + lr) * 32 + lg * 8];
            f32x4 acc[16] = {};
            #pragma unroll
            for (int ni = 0; ni < 16; ++ni) {
                bf16x8 b = *(const bf16x8*)(W0t + (size_t)(wc * 256 + ni * 16 + lr) * 32 + lg * 8);
                acc[ni] = __builtin_amdgcn_mfma_f32_16x16x32_bf16(a, b, acc[ni], 0, 0, 0);
            }
            #pragma unroll
            for (int ni = 0; ni < 16; ++ni) {
                int col = wc * 256 + ni * 16 + lr;
                float bv = b0[col];
                #pragma unroll
                for (int j = 0; j < 4; ++j) {
                    int r = wr * 16 + lg * 4 + j;
                    X1s[r * X1STR + col] = f2bf(fmaxf(acc[ni][j] + bv, 0.f));
                }
            }
        }
        // phase 1: X2 = relu(X1 @ W1^T + b1): 32x256, K=512 (16 steps)
        {
            f32x4 acc[8] = {};
            for (int k0 = 0; k0 < 512; k0 += 32) {
                #pragma unroll
                for (int rd = 0; rd < 4; ++rd) {
                    int slot = rd * 256 + tid;
                    int n = slot >> 2, kc = slot & 3;
                    gload_lds16(W1t + (size_t)n * 512 + k0 + (kc ^ (n & 3)) * 8, &Bst[slot * 8]);
                }
                __syncthreads();
                bf16x8 a = *(const bf16x8*)&X1s[(wr * 16 + lr) * X1STR + k0 + lg * 8];
                #pragma unroll
                for (int ni = 0; ni < 8; ++ni) {
                    int n = wc * 128 + ni * 16 + lr;
                    bf16x8 b = *(const bf16x8*)&Bst[n * 32 + swz];
                    acc[ni] = __builtin_amdgcn_mfma_f32_16x16x32_bf16(a, b, acc[ni], 0, 0, 0);
                }
                __syncthreads();
            }
            #pragma unroll
            for (int ni = 0; ni < 8; ++ni) {
                int col = wc * 128 + ni * 16 + lr;
                float bv = b1[col];
                #pragma unroll
                for (int j = 0; j < 4; ++j) {
                    int r = wr * 16 + lg * 4 + j;
                    X2s[r * X2STR + col] = f2bf(fmaxf(acc[ni][j] + bv, 0.f));
                }
            }
        }
        // phase 2: dense_out = relu(X2 @ W2^T + b2): 32x64, K=256 (8 steps)
        {
            f32x4 acc[2] = {};
            for (int k0 = 0; k0 < 256; k0 += 32) {
                {
                    int n = tid >> 2, kc = tid & 3;
                    gload_lds16(W2t + (size_t)n * 256 + k0 + (kc ^ (n & 3)) * 8, &Bst[tid * 8]);
                }
                __syncthreads();
                bf16x8 a = *(const bf16x8*)&X2s[(wr * 16 + lr) * X2STR + k0 + lg * 8];
                #pragma unroll
                for (int ni = 0; ni < 2; ++ni) {
                    int n = wc * 32 + ni * 16 + lr;
                    bf16x8 b = *(const bf16x8*)&Bst[n * 32 + swz];
                    acc[ni] = __builtin_amdgcn_mfma_f32_16x16x32_bf16(a, b, acc[ni], 0, 0, 0);
                }
                __syncthreads();
            }
            #pragma unroll
            for (int ni = 0; ni < 2; ++ni) {
                int col = wc * 32 + ni * 16 + lr;
                float bv = b2[col];
                #pragma unroll
                for (int j = 0; j < 4; ++j) {
                    int r = wr * 16 + lg * 4 + j;
                    As[r * ASTR + col] = f2bf(fmaxf(acc[ni][j] + bv, 0.f));
                }
            }
        }
    };

    // stagger: co-resident blocks are ~(i, i+256) -> opposite phase order
    // must come from bit 8, not bit 0.
    if ((blockIdx.x >> 8) & 1) { mlp_phase(); gram_phase(); }
    else                       { gram_phase(); mlp_phase(); }

    // ---- top GEMM: out(32x256) = As(32xK416) @ Wtt^T + bt ----
    {
        f32x4 acc[8] = {};
        for (int k0 = 0; k0 < KTOP; k0 += 32) {
            #pragma unroll
            for (int rd = 0; rd < 4; ++rd) {
                int slot = rd * 256 + tid;
                int n = slot >> 2, kc = slot & 3;
                gload_lds16(Wtt + (size_t)n * KTOP + k0 + (kc ^ (n & 3)) * 8, &Bst[slot * 8]);
            }
            __syncthreads();
            bf16x8 a = *(const bf16x8*)&As[(wr * 16 + lr) * ASTR + k0 + lg * 8];
            #pragma unroll
            for (int ni = 0; ni < 8; ++ni) {
                int n = wc * 128 + ni * 16 + lr;
                bf16x8 b = *(const bf16x8*)&Bst[n * 32 + swz];
                acc[ni] = __builtin_amdgcn_mfma_f32_16x16x32_bf16(a, b, acc[ni], 0, 0, 0);
            }
            __syncthreads();
        }
        #pragma unroll
        for (int ni = 0; ni < 8; ++ni) {
            int col = wc * 128 + ni * 16 + lr;
            float bv = bt[col];
            #pragma unroll
            for (int j = 0; j < 4; ++j) {
                int r = wr * 16 + lg * 4 + j;
                out[(size_t)(sbase + r) * 256 + col] = acc[ni][j] + bv;
            }
        }
    }
}

// -------------------------------------------------------------- launch ----
extern "C" void kernel_launch(void* const* d_in, const int* in_sizes, int n_in,
                              void* d_out, int out_size, void* d_ws, size_t ws_size,
                              hipStream_t stream)
{
    const float* dense  = (const float*)d_in[0];
    const int*   sparse = (const int*)  d_in[1];
    const float* tables = (const float*)d_in[2];
    const float* W0     = (const float*)d_in[3];
    const float* b0     = (const float*)d_in[4];
    const float* W1     = (const float*)d_in[5];
    const float* b1     = (const float*)d_in[6];
    const float* W2     = (const float*)d_in[7];
    const float* b2     = (const float*)d_in[8];
    const float* Wt     = (const float*)d_in[9];
    const float* bt     = (const float*)d_in[10];
    float* out = (float*)d_out;

    char* ws = (char*)d_ws;
    short* W0t = (short*)(ws);
    short* W1t = (short*)(ws + 32768);
    short* W2t = (short*)(ws + 294912);
    short* Wtt = (short*)(ws + 327680);

    prep_weights<<<264, 256, 0, stream>>>(W0, W1, W2, Wt, W0t, W1t, W2t, Wtt);

    fused_all<<<BATCH / SPB, 256, 0, stream>>>(sparse, tables, dense,
                                               W0t, b0, W1t, b1, W2t, b2,
                                               Wtt, bt, out);
}